// Round 1
// baseline (5891.739 us; speedup 1.0000x reference)
//
#include <hip/hip_runtime.h>

#define NEG_SLOPE 0.01f

// ---------------------------------------------------------------------------
// deg[i] = number of edges with dst == i
// ---------------------------------------------------------------------------
__global__ __launch_bounds__(256) void deg_kernel(const int* __restrict__ dst,
                                                  float* __restrict__ deg, int E) {
    int e = blockIdx.x * blockDim.x + threadIdx.x;
    if (e < E) atomicAdd(&deg[dst[e]], 1.0f);
}

// ---------------------------------------------------------------------------
// accum[dst[e]][:] += x[src[e]][:]   (32 threads per edge, float4 each)
// ---------------------------------------------------------------------------
__global__ __launch_bounds__(256) void scatter_kernel(const float* __restrict__ x,
                                                      const int* __restrict__ src,
                                                      const int* __restrict__ dst,
                                                      float* __restrict__ accum, int E) {
    int t = blockIdx.x * blockDim.x + threadIdx.x;
    int total = E * 32;
    if (t >= total) return;
    int e = t >> 5;
    int q = t & 31;
    int s = src[e];
    int d = dst[e];
    float4 v = ((const float4*)(x + (long long)s * 128))[q];
    float* ar = accum + (long long)d * 128 + q * 4;
    atomicAdd(ar + 0, v.x);
    atomicAdd(ar + 1, v.y);
    atomicAdd(ar + 2, v.z);
    atomicAdd(ar + 3, v.w);
}

// ---------------------------------------------------------------------------
// out[r][c] = leaky( sum_k ((accum[r][k]+xin[r][k])/(deg[r]+1)) * W[k][c] + b[c] )
// 64 rows per block, 256 threads = 2 rows x 128 cols, W k-chunked (2 x 32KB LDS).
// In-place safe (out == xin): each block reads only its own rows into LDS
// before writing them, and row sets of different blocks are disjoint.
// ---------------------------------------------------------------------------
__global__ __launch_bounds__(256) void fused_gemm(const float* __restrict__ xin,
                                                  const float* __restrict__ accum,
                                                  const float* __restrict__ deg,
                                                  const float* __restrict__ W,
                                                  const float* __restrict__ b,
                                                  float* __restrict__ out, int N) {
    __shared__ float Hs[64 * 128];   // 32 KB
    __shared__ float Wsh[64 * 128];  // 32 KB (one k-chunk of W)
    const int tid = threadIdx.x;
    const int row0 = blockIdx.x * 64;

    // Load + normalize 64-row H tile (float4 per thread-iteration)
    for (int i = tid; i < 64 * 32; i += 256) {
        int r = i >> 5, q = i & 31;
        int gr = row0 + r;
        float4 h = make_float4(0.f, 0.f, 0.f, 0.f);
        if (gr < N) {
            float4 a = ((const float4*)accum)[(long long)gr * 32 + q];
            float4 f = ((const float4*)xin)[(long long)gr * 32 + q];
            float inv = 1.0f / (deg[gr] + 1.0f);
            h.x = (a.x + f.x) * inv;
            h.y = (a.y + f.y) * inv;
            h.z = (a.z + f.z) * inv;
            h.w = (a.w + f.w) * inv;
        }
        ((float4*)Hs)[i] = h;
    }

    const int c = tid & 127;
    const int rr = tid >> 7;  // 0 or 1
    float acc[32];
#pragma unroll
    for (int i = 0; i < 32; ++i) acc[i] = 0.f;

    for (int kc = 0; kc < 2; ++kc) {
        __syncthreads();
        for (int i = tid; i < 64 * 32; i += 256)
            ((float4*)Wsh)[i] = ((const float4*)W)[kc * 64 * 32 + i];
        __syncthreads();
#pragma unroll
        for (int ri = 0; ri < 32; ++ri) {
            int r = rr + ri * 2;
            const float* hrow = Hs + r * 128 + kc * 64;
            float a = acc[ri];
#pragma unroll 8
            for (int k = 0; k < 64; ++k) a += hrow[k] * Wsh[k * 128 + c];
            acc[ri] = a;
        }
    }

    const float bias = b[c];
    for (int ri = 0; ri < 32; ++ri) {
        int r = rr + ri * 2;
        int gr = row0 + r;
        if (gr < N) {
            float v = acc[ri] + bias;
            v = v > 0.f ? v : v * NEG_SLOPE;
            out[(long long)gr * 128 + c] = v;
        }
    }
}

extern "C" void kernel_launch(void* const* d_in, const int* in_sizes, int n_in,
                              void* d_out, int out_size, void* d_ws, size_t ws_size,
                              hipStream_t stream) {
    const float* feat = (const float*)d_in[0];
    const int*   edges = (const int*)d_in[1];
    const float* W1 = (const float*)d_in[2];
    const float* b1 = (const float*)d_in[3];
    const float* W2 = (const float*)d_in[4];
    const float* b2 = (const float*)d_in[5];
    float* out = (float*)d_out;

    const int N = in_sizes[0] / 128;
    const int E = in_sizes[1] / 2;
    const int* src = edges;
    const int* dst = edges + E;

    float* deg   = (float*)d_ws;      // N floats
    float* accum = deg + N;           // N*128 floats

    // Zero deg + accum (ws is poisoned to 0xAA before every timed launch)
    hipMemsetAsync(d_ws, 0, (size_t)(N + (size_t)N * 128) * sizeof(float), stream);

    deg_kernel<<<(E + 255) / 256, 256, 0, stream>>>(dst, deg, E);

    // ---- Layer 1 ----
    scatter_kernel<<<(E * 32 + 255) / 256, 256, 0, stream>>>(feat, src, dst, accum, E);
    fused_gemm<<<(N + 63) / 64, 256, 0, stream>>>(feat, accum, deg, W1, b1, out, N);

    // ---- Layer 2 (h1 lives in d_out; GEMM is in-place safe) ----
    hipMemsetAsync(accum, 0, (size_t)N * 128 * sizeof(float), stream);
    scatter_kernel<<<(E * 32 + 255) / 256, 256, 0, stream>>>(out, src, dst, accum, E);
    fused_gemm<<<(N + 63) / 64, 256, 0, stream>>>(out, accum, deg, W2, b2, out, N);
}

// Round 2
// 1173.862 us; speedup vs baseline: 5.0191x; 5.0191x over previous
//
#include <hip/hip_runtime.h>

#define NEG_SLOPE 0.01f

// ---------------------------------------------------------------------------
// counts[dst[e]] += 1  (int atomics, cheap)
// ---------------------------------------------------------------------------
__global__ __launch_bounds__(256) void count_kernel(const int* __restrict__ dst,
                                                    int* __restrict__ counts, int E) {
    int e = blockIdx.x * blockDim.x + threadIdx.x;
    if (e < E) atomicAdd(&counts[dst[e]], 1);
}

// ---------------------------------------------------------------------------
// Single-block exclusive scan over N counts -> offsets[0..N], cursor[0..N-1].
// counts and cursor may alias (read-then-write per element by same thread).
// ---------------------------------------------------------------------------
__global__ __launch_bounds__(1024) void scan_kernel(const int* __restrict__ counts,
                                                    int* __restrict__ offsets,
                                                    int* __restrict__ cursor, int N) {
    __shared__ int part[1024];
    const int t = threadIdx.x;
    const int chunk = (N + 1023) / 1024;
    const int lo = t * chunk;
    const int hi = min(lo + chunk, N);
    int s = 0;
    for (int i = lo; i < hi; ++i) s += counts[i];
    part[t] = s;
    __syncthreads();
    // Hillis-Steele inclusive scan of partials
    for (int d = 1; d < 1024; d <<= 1) {
        int v = (t >= d) ? part[t - d] : 0;
        __syncthreads();
        part[t] += v;
        __syncthreads();
    }
    int run = part[t] - s;  // exclusive prefix for this thread's chunk
    for (int i = lo; i < hi; ++i) {
        int c = counts[i];
        offsets[i] = run;
        cursor[i] = run;
        run += c;
    }
    if (t == 1023) offsets[N] = part[1023];  // total edge count
}

// ---------------------------------------------------------------------------
// csr[pos] = src[e] where pos = cursor[dst[e]]++
// ---------------------------------------------------------------------------
__global__ __launch_bounds__(256) void fill_kernel(const int* __restrict__ src,
                                                   const int* __restrict__ dst,
                                                   int* __restrict__ cursor,
                                                   int* __restrict__ csr, int E) {
    int e = blockIdx.x * blockDim.x + threadIdx.x;
    if (e < E) {
        int pos = atomicAdd(&cursor[dst[e]], 1);
        csr[pos] = src[e];
    }
}

// ---------------------------------------------------------------------------
// H[n][:] = (x[n][:] + sum_{s in csr[offsets[n]:offsets[n+1]]} x[s][:]) / (deg+1)
// One wave (64 lanes) per node, float2 per lane, 2-way unrolled.
// ---------------------------------------------------------------------------
__global__ __launch_bounds__(256) void aggregate_kernel(const float* __restrict__ x,
                                                        const int* __restrict__ offsets,
                                                        const int* __restrict__ csr,
                                                        float* __restrict__ H, int N) {
    const int node = (blockIdx.x * blockDim.x + threadIdx.x) >> 6;
    const int lane = threadIdx.x & 63;
    if (node >= N) return;
    const int start = offsets[node];
    const int end   = offsets[node + 1];
    const float2* x2 = (const float2*)x;

    float2 a0 = x2[(long long)node * 64 + lane];  // self feature
    float2 a1 = make_float2(0.f, 0.f);
    int j = start;
    for (; j + 2 <= end; j += 2) {
        int s0 = csr[j];
        int s1 = csr[j + 1];
        float2 v0 = x2[(long long)s0 * 64 + lane];
        float2 v1 = x2[(long long)s1 * 64 + lane];
        a0.x += v0.x; a0.y += v0.y;
        a1.x += v1.x; a1.y += v1.y;
    }
    if (j < end) {
        int s0 = csr[j];
        float2 v0 = x2[(long long)s0 * 64 + lane];
        a0.x += v0.x; a0.y += v0.y;
    }
    const float inv = 1.0f / (float)(end - start + 1);
    float2 r;
    r.x = (a0.x + a1.x) * inv;
    r.y = (a0.y + a1.y) * inv;
    ((float2*)H)[(long long)node * 64 + lane] = r;
}

// ---------------------------------------------------------------------------
// out[r][c] = leaky( sum_k H[r][k] * W[k][c] + b[c] )
// 64 rows/block, 256 threads = 2 rows x 128 cols, W k-chunked (2 x 32KB LDS).
// ---------------------------------------------------------------------------
__global__ __launch_bounds__(256) void fused_gemm(const float* __restrict__ H,
                                                  const float* __restrict__ W,
                                                  const float* __restrict__ b,
                                                  float* __restrict__ out, int N) {
    __shared__ float Hs[64 * 128];   // 32 KB
    __shared__ float Wsh[64 * 128];  // 32 KB (one k-chunk of W)
    const int tid = threadIdx.x;
    const int row0 = blockIdx.x * 64;

    for (int i = tid; i < 64 * 32; i += 256) {
        int r = i >> 5, q = i & 31;
        int gr = row0 + r;
        float4 h = make_float4(0.f, 0.f, 0.f, 0.f);
        if (gr < N) h = ((const float4*)H)[(long long)gr * 32 + q];
        ((float4*)Hs)[i] = h;
    }

    const int c = tid & 127;
    const int rr = tid >> 7;  // 0 or 1
    float acc[32];
#pragma unroll
    for (int i = 0; i < 32; ++i) acc[i] = 0.f;

    for (int kc = 0; kc < 2; ++kc) {
        __syncthreads();
        for (int i = tid; i < 64 * 32; i += 256)
            ((float4*)Wsh)[i] = ((const float4*)W)[kc * 64 * 32 + i];
        __syncthreads();
#pragma unroll
        for (int ri = 0; ri < 32; ++ri) {
            int r = rr + ri * 2;
            const float* hrow = Hs + r * 128 + kc * 64;
            float a = acc[ri];
#pragma unroll 8
            for (int k = 0; k < 64; ++k) a += hrow[k] * Wsh[k * 128 + c];
            acc[ri] = a;
        }
    }

    const float bias = b[c];
    for (int ri = 0; ri < 32; ++ri) {
        int r = rr + ri * 2;
        int gr = row0 + r;
        if (gr < N) {
            float v = acc[ri] + bias;
            v = v > 0.f ? v : v * NEG_SLOPE;
            out[(long long)gr * 128 + c] = v;
        }
    }
}

extern "C" void kernel_launch(void* const* d_in, const int* in_sizes, int n_in,
                              void* d_out, int out_size, void* d_ws, size_t ws_size,
                              hipStream_t stream) {
    const float* feat = (const float*)d_in[0];
    const int*   edges = (const int*)d_in[1];
    const float* W1 = (const float*)d_in[2];
    const float* b1 = (const float*)d_in[3];
    const float* W2 = (const float*)d_in[4];
    const float* b2 = (const float*)d_in[5];
    float* out = (float*)d_out;

    const int N = in_sizes[0] / 128;
    const int E = in_sizes[1] / 2;
    const int* src = edges;
    const int* dst = edges + E;

    // Workspace layout (H first for 16B alignment of float4 loads):
    //   H:       N*128 floats  (51.2 MB)
    //   offsets: N+1 ints
    //   cursor:  N ints        (also used as counts)
    //   csr:     E ints        (6.4 MB)
    float* H       = (float*)d_ws;
    int*   offsets = (int*)(H + (size_t)N * 128);
    int*   cursor  = offsets + (N + 1);
    int*   csr     = cursor + N;

    // ---- Build CSR (dst -> list of src), shared by both layers ----
    hipMemsetAsync(cursor, 0, (size_t)N * sizeof(int), stream);
    count_kernel<<<(E + 255) / 256, 256, 0, stream>>>(dst, cursor, E);
    scan_kernel<<<1, 1024, 0, stream>>>(cursor, offsets, cursor, N);
    fill_kernel<<<(E + 255) / 256, 256, 0, stream>>>(src, dst, cursor, csr, E);

    const int aggGrid = (N + 3) / 4;   // 4 nodes (waves) per 256-thread block
    const int gemmGrid = (N + 63) / 64;

    // ---- Layer 1 ----
    aggregate_kernel<<<aggGrid, 256, 0, stream>>>(feat, offsets, csr, H, N);
    fused_gemm<<<gemmGrid, 256, 0, stream>>>(H, W1, b1, out, N);

    // ---- Layer 2 ----
    aggregate_kernel<<<aggGrid, 256, 0, stream>>>(out, offsets, csr, H, N);
    fused_gemm<<<gemmGrid, 256, 0, stream>>>(H, W2, b2, out, N);
}

// Round 3
// 946.019 us; speedup vs baseline: 6.2279x; 1.2408x over previous
//
#include <hip/hip_runtime.h>

#define NEG_SLOPE 0.01f
#define SCAN_CHUNK 1024  // counts per block in the hierarchical scan

// ---------------------------------------------------------------------------
// counts[dst[e]] += 1  (int atomics, cheap)
// ---------------------------------------------------------------------------
__global__ __launch_bounds__(256) void count_kernel(const int* __restrict__ dst,
                                                    int* __restrict__ counts, int E) {
    int e = blockIdx.x * blockDim.x + threadIdx.x;
    if (e < E) atomicAdd(&counts[dst[e]], 1);
}

// ---------------------------------------------------------------------------
// Phase 1: block b sums counts[b*1024 .. b*1024+1023] -> bsum[b]
// ---------------------------------------------------------------------------
__global__ __launch_bounds__(256) void scan_reduce(const int* __restrict__ counts,
                                                   int* __restrict__ bsum, int N) {
    __shared__ int red[256];
    const int t = threadIdx.x;
    const int base = blockIdx.x * SCAN_CHUNK + t * 4;
    int s = 0;
#pragma unroll
    for (int k = 0; k < 4; ++k) {
        int i = base + k;
        if (i < N) s += counts[i];
    }
    red[t] = s;
    __syncthreads();
    for (int d = 128; d > 0; d >>= 1) {
        if (t < d) red[t] += red[t + d];
        __syncthreads();
    }
    if (t == 0) bsum[blockIdx.x] = red[0];
}

// ---------------------------------------------------------------------------
// Phase 2: one block exclusive-scans nb (<=128) block sums in place,
// writes grand total to offsets[N].
// ---------------------------------------------------------------------------
__global__ __launch_bounds__(128) void scan_top(int* __restrict__ bsum,
                                                int* __restrict__ offsets,
                                                int nb, int N) {
    __shared__ int sh[128];
    const int t = threadIdx.x;
    int v = (t < nb) ? bsum[t] : 0;
    sh[t] = v;
    __syncthreads();
    for (int d = 1; d < 128; d <<= 1) {
        int u = (t >= d) ? sh[t - d] : 0;
        __syncthreads();
        sh[t] += u;
        __syncthreads();
    }
    if (t < nb) bsum[t] = sh[t] - v;           // exclusive prefix
    if (t == 127) offsets[N] = sh[127];        // grand total (== E)
}

// ---------------------------------------------------------------------------
// Phase 3: block b re-scans its 1024 counts (exclusive), adds bsum[b],
// writes offsets[i] and cursor[i].
// ---------------------------------------------------------------------------
__global__ __launch_bounds__(256) void scan_write(const int* __restrict__ counts,
                                                  const int* __restrict__ bsum,
                                                  int* __restrict__ offsets,
                                                  int* __restrict__ cursor, int N) {
    __shared__ int sh[256];
    const int t = threadIdx.x;
    const int base = blockIdx.x * SCAN_CHUNK + t * 4;
    int c[4];
    int s = 0;
#pragma unroll
    for (int k = 0; k < 4; ++k) {
        int i = base + k;
        c[k] = (i < N) ? counts[i] : 0;
        s += c[k];
    }
    sh[t] = s;
    __syncthreads();
    for (int d = 1; d < 256; d <<= 1) {
        int u = (t >= d) ? sh[t - d] : 0;
        __syncthreads();
        sh[t] += u;
        __syncthreads();
    }
    int run = bsum[blockIdx.x] + sh[t] - s;    // exclusive prefix for this thread
#pragma unroll
    for (int k = 0; k < 4; ++k) {
        int i = base + k;
        if (i < N) {
            offsets[i] = run;
            cursor[i] = run;
            run += c[k];
        }
    }
}

// ---------------------------------------------------------------------------
// csr[pos] = src[e] where pos = cursor[dst[e]]++
// ---------------------------------------------------------------------------
__global__ __launch_bounds__(256) void fill_kernel(const int* __restrict__ src,
                                                   const int* __restrict__ dst,
                                                   int* __restrict__ cursor,
                                                   int* __restrict__ csr, int E) {
    int e = blockIdx.x * blockDim.x + threadIdx.x;
    if (e < E) {
        int pos = atomicAdd(&cursor[dst[e]], 1);
        csr[pos] = src[e];
    }
}

// ---------------------------------------------------------------------------
// H[n][:] = (x[n][:] + sum_{s in csr[offsets[n]:offsets[n+1]]} x[s][:]) / (deg+1)
// One wave (64 lanes) per node, float2 per lane, 2-way unrolled.
// ---------------------------------------------------------------------------
__global__ __launch_bounds__(256) void aggregate_kernel(const float* __restrict__ x,
                                                        const int* __restrict__ offsets,
                                                        const int* __restrict__ csr,
                                                        float* __restrict__ H, int N) {
    const int node = (blockIdx.x * blockDim.x + threadIdx.x) >> 6;
    const int lane = threadIdx.x & 63;
    if (node >= N) return;
    const int start = offsets[node];
    const int end   = offsets[node + 1];
    const float2* x2 = (const float2*)x;

    float2 a0 = x2[(long long)node * 64 + lane];  // self feature
    float2 a1 = make_float2(0.f, 0.f);
    int j = start;
    for (; j + 2 <= end; j += 2) {
        int s0 = csr[j];
        int s1 = csr[j + 1];
        float2 v0 = x2[(long long)s0 * 64 + lane];
        float2 v1 = x2[(long long)s1 * 64 + lane];
        a0.x += v0.x; a0.y += v0.y;
        a1.x += v1.x; a1.y += v1.y;
    }
    if (j < end) {
        int s0 = csr[j];
        float2 v0 = x2[(long long)s0 * 64 + lane];
        a0.x += v0.x; a0.y += v0.y;
    }
    const float inv = 1.0f / (float)(end - start + 1);
    float2 r;
    r.x = (a0.x + a1.x) * inv;
    r.y = (a0.y + a1.y) * inv;
    ((float2*)H)[(long long)node * 64 + lane] = r;
}

// ---------------------------------------------------------------------------
// out[r][c] = leaky( sum_k H[r][k] * W[k][c] + b[c] )
// 64 rows/block, 256 threads = 2 rows x 128 cols, W k-chunked (2 x 32KB LDS).
// ---------------------------------------------------------------------------
__global__ __launch_bounds__(256) void fused_gemm(const float* __restrict__ H,
                                                  const float* __restrict__ W,
                                                  const float* __restrict__ b,
                                                  float* __restrict__ out, int N) {
    __shared__ float Hs[64 * 128];   // 32 KB
    __shared__ float Wsh[64 * 128];  // 32 KB (one k-chunk of W)
    const int tid = threadIdx.x;
    const int row0 = blockIdx.x * 64;

    for (int i = tid; i < 64 * 32; i += 256) {
        int r = i >> 5, q = i & 31;
        int gr = row0 + r;
        float4 h = make_float4(0.f, 0.f, 0.f, 0.f);
        if (gr < N) h = ((const float4*)H)[(long long)gr * 32 + q];
        ((float4*)Hs)[i] = h;
    }

    const int c = tid & 127;
    const int rr = tid >> 7;  // 0 or 1
    float acc[32];
#pragma unroll
    for (int i = 0; i < 32; ++i) acc[i] = 0.f;

    for (int kc = 0; kc < 2; ++kc) {
        __syncthreads();
        for (int i = tid; i < 64 * 32; i += 256)
            ((float4*)Wsh)[i] = ((const float4*)W)[kc * 64 * 32 + i];
        __syncthreads();
#pragma unroll
        for (int ri = 0; ri < 32; ++ri) {
            int r = rr + ri * 2;
            const float* hrow = Hs + r * 128 + kc * 64;
            float a = acc[ri];
#pragma unroll 8
            for (int k = 0; k < 64; ++k) a += hrow[k] * Wsh[k * 128 + c];
            acc[ri] = a;
        }
    }

    const float bias = b[c];
    for (int ri = 0; ri < 32; ++ri) {
        int r = rr + ri * 2;
        int gr = row0 + r;
        if (gr < N) {
            float v = acc[ri] + bias;
            v = v > 0.f ? v : v * NEG_SLOPE;
            out[(long long)gr * 128 + c] = v;
        }
    }
}

extern "C" void kernel_launch(void* const* d_in, const int* in_sizes, int n_in,
                              void* d_out, int out_size, void* d_ws, size_t ws_size,
                              hipStream_t stream) {
    const float* feat = (const float*)d_in[0];
    const int*   edges = (const int*)d_in[1];
    const float* W1 = (const float*)d_in[2];
    const float* b1 = (const float*)d_in[3];
    const float* W2 = (const float*)d_in[4];
    const float* b2 = (const float*)d_in[5];
    float* out = (float*)d_out;

    const int N = in_sizes[0] / 128;
    const int E = in_sizes[1] / 2;
    const int* src = edges;
    const int* dst = edges + E;

    // Workspace layout (H first for 16B alignment of float4 loads):
    //   H:       N*128 floats  (51.2 MB)
    //   offsets: N+1 ints
    //   counts:  N ints   (becomes cursor after scan_write)
    //   bsum:    128 ints (scan block partials)
    //   csr:     E ints   (6.4 MB)
    float* H       = (float*)d_ws;
    int*   offsets = (int*)(H + (size_t)N * 128);
    int*   counts  = offsets + (N + 1);     // aliased as cursor
    int*   bsum    = counts + N;
    int*   csr     = bsum + 128;

    const int nb = (N + SCAN_CHUNK - 1) / SCAN_CHUNK;   // 98 for N=100k

    // ---- Build CSR (dst -> list of src), shared by both layers ----
    hipMemsetAsync(counts, 0, (size_t)N * sizeof(int), stream);
    count_kernel<<<(E + 255) / 256, 256, 0, stream>>>(dst, counts, E);
    scan_reduce<<<nb, 256, 0, stream>>>(counts, bsum, N);
    scan_top<<<1, 128, 0, stream>>>(bsum, offsets, nb, N);
    scan_write<<<nb, 256, 0, stream>>>(counts, bsum, offsets, counts, N);
    fill_kernel<<<(E + 255) / 256, 256, 0, stream>>>(src, dst, counts, csr, E);

    const int aggGrid = (N + 3) / 4;   // 4 nodes (waves) per 256-thread block
    const int gemmGrid = (N + 63) / 64;

    // ---- Layer 1 ----
    aggregate_kernel<<<aggGrid, 256, 0, stream>>>(feat, offsets, csr, H, N);
    fused_gemm<<<gemmGrid, 256, 0, stream>>>(H, W1, b1, out, N);

    // ---- Layer 2 ----
    aggregate_kernel<<<aggGrid, 256, 0, stream>>>(out, offsets, csr, H, N);
    fused_gemm<<<gemmGrid, 256, 0, stream>>>(H, W2, b2, out, N);
}

// Round 4
// 771.787 us; speedup vs baseline: 7.6339x; 1.2258x over previous
//
#include <hip/hip_runtime.h>

#define NEG_SLOPE 0.01f
#define SCAN_CHUNK 1024  // counts per block in the hierarchical scan

// ---------------------------------------------------------------------------
// counts[dst[e]] += 1  (int atomics, cheap)
// ---------------------------------------------------------------------------
__global__ __launch_bounds__(256) void count_kernel(const int* __restrict__ dst,
                                                    int* __restrict__ counts, int E) {
    int e = blockIdx.x * blockDim.x + threadIdx.x;
    if (e < E) atomicAdd(&counts[dst[e]], 1);
}

// ---------------------------------------------------------------------------
// Phase 1: block b sums counts[b*1024 .. b*1024+1023] -> bsum[b]
// ---------------------------------------------------------------------------
__global__ __launch_bounds__(256) void scan_reduce(const int* __restrict__ counts,
                                                   int* __restrict__ bsum, int N) {
    __shared__ int red[256];
    const int t = threadIdx.x;
    const int base = blockIdx.x * SCAN_CHUNK + t * 4;
    int s = 0;
#pragma unroll
    for (int k = 0; k < 4; ++k) {
        int i = base + k;
        if (i < N) s += counts[i];
    }
    red[t] = s;
    __syncthreads();
    for (int d = 128; d > 0; d >>= 1) {
        if (t < d) red[t] += red[t + d];
        __syncthreads();
    }
    if (t == 0) bsum[blockIdx.x] = red[0];
}

// ---------------------------------------------------------------------------
// Phase 2: one block exclusive-scans nb (<=128) block sums in place,
// writes grand total to offsets[N].
// ---------------------------------------------------------------------------
__global__ __launch_bounds__(128) void scan_top(int* __restrict__ bsum,
                                                int* __restrict__ offsets,
                                                int nb, int N) {
    __shared__ int sh[128];
    const int t = threadIdx.x;
    int v = (t < nb) ? bsum[t] : 0;
    sh[t] = v;
    __syncthreads();
    for (int d = 1; d < 128; d <<= 1) {
        int u = (t >= d) ? sh[t - d] : 0;
        __syncthreads();
        sh[t] += u;
        __syncthreads();
    }
    if (t < nb) bsum[t] = sh[t] - v;           // exclusive prefix
    if (t == 127) offsets[N] = sh[127];        // grand total (== E)
}

// ---------------------------------------------------------------------------
// Phase 3: block b re-scans its 1024 counts (exclusive), adds bsum[b],
// writes offsets[i] and cursor[i].
// ---------------------------------------------------------------------------
__global__ __launch_bounds__(256) void scan_write(const int* __restrict__ counts,
                                                  const int* __restrict__ bsum,
                                                  int* __restrict__ offsets,
                                                  int* __restrict__ cursor, int N) {
    __shared__ int sh[256];
    const int t = threadIdx.x;
    const int base = blockIdx.x * SCAN_CHUNK + t * 4;
    int c[4];
    int s = 0;
#pragma unroll
    for (int k = 0; k < 4; ++k) {
        int i = base + k;
        c[k] = (i < N) ? counts[i] : 0;
        s += c[k];
    }
    sh[t] = s;
    __syncthreads();
    for (int d = 1; d < 256; d <<= 1) {
        int u = (t >= d) ? sh[t - d] : 0;
        __syncthreads();
        sh[t] += u;
        __syncthreads();
    }
    int run = bsum[blockIdx.x] + sh[t] - s;    // exclusive prefix for this thread
#pragma unroll
    for (int k = 0; k < 4; ++k) {
        int i = base + k;
        if (i < N) {
            offsets[i] = run;
            cursor[i] = run;
            run += c[k];
        }
    }
}

// ---------------------------------------------------------------------------
// csr[pos] = src[e] where pos = cursor[dst[e]]++
// ---------------------------------------------------------------------------
__global__ __launch_bounds__(256) void fill_kernel(const int* __restrict__ src,
                                                   const int* __restrict__ dst,
                                                   int* __restrict__ cursor,
                                                   int* __restrict__ csr, int E) {
    int e = blockIdx.x * blockDim.x + threadIdx.x;
    if (e < E) {
        int pos = atomicAdd(&cursor[dst[e]], 1);
        csr[pos] = src[e];
    }
}

// ---------------------------------------------------------------------------
// H[n][:] = (x[n][:] + sum_{s in csr[offsets[n]:offsets[n+1]]} x[s][:]) / (deg+1)
// One wave (64 lanes) per node, float2 per lane, 2-way unrolled.
// ---------------------------------------------------------------------------
__global__ __launch_bounds__(256) void aggregate_kernel(const float* __restrict__ x,
                                                        const int* __restrict__ offsets,
                                                        const int* __restrict__ csr,
                                                        float* __restrict__ H, int N) {
    const int node = (blockIdx.x * blockDim.x + threadIdx.x) >> 6;
    const int lane = threadIdx.x & 63;
    if (node >= N) return;
    const int start = offsets[node];
    const int end   = offsets[node + 1];
    const float2* x2 = (const float2*)x;

    float2 a0 = x2[(long long)node * 64 + lane];  // self feature
    float2 a1 = make_float2(0.f, 0.f);
    int j = start;
    for (; j + 2 <= end; j += 2) {
        int s0 = csr[j];
        int s1 = csr[j + 1];
        float2 v0 = x2[(long long)s0 * 64 + lane];
        float2 v1 = x2[(long long)s1 * 64 + lane];
        a0.x += v0.x; a0.y += v0.y;
        a1.x += v1.x; a1.y += v1.y;
    }
    if (j < end) {
        int s0 = csr[j];
        float2 v0 = x2[(long long)s0 * 64 + lane];
        a0.x += v0.x; a0.y += v0.y;
    }
    const float inv = 1.0f / (float)(end - start + 1);
    float2 r;
    r.x = (a0.x + a1.x) * inv;
    r.y = (a0.y + a1.y) * inv;
    ((float2*)H)[(long long)node * 64 + lane] = r;
}

// ---------------------------------------------------------------------------
// out[r][c] = leaky( sum_k H[r][k] * W[k][c] + b[c] )
// 64 rows/block, 256 threads; thread (tr,tc) = (tid>>5, tid&31) computes an
// 8-row x 4-col register tile: rows tr*8..tr*8+7, cols tc*4..tc*4+3.
// Per 4-k step: 8 ds_read_b128 (H, 2-addr broadcast) + 4 ds_read_b128 (W,
// conflict-free) feed 128 FMAs -> FMA-bound (~2 cyc/FMA vs 13.6 before).
// W k-chunked 2 x 32KB; LDS total 64KB -> 2 blocks/CU.
// ---------------------------------------------------------------------------
__global__ __launch_bounds__(256) void fused_gemm(const float* __restrict__ H,
                                                  const float* __restrict__ W,
                                                  const float* __restrict__ b,
                                                  float* __restrict__ out, int N) {
    __shared__ float Hs[64 * 128];   // 32 KB (full 128-k for 64 rows)
    __shared__ float Wsh[64 * 128];  // 32 KB (one 64-k chunk of W, [k][c])
    const int tid = threadIdx.x;
    const int row0 = blockIdx.x * 64;
    const int tr = tid >> 5;         // 0..7  (row group: rows tr*8..tr*8+7)
    const int tc = tid & 31;         // 0..31 (col group: cols tc*4..tc*4+3)

    // Load 64-row H tile
    for (int i = tid; i < 64 * 32; i += 256) {
        int r = i >> 5, q = i & 31;
        int gr = row0 + r;
        float4 h = make_float4(0.f, 0.f, 0.f, 0.f);
        if (gr < N) h = ((const float4*)H)[(long long)gr * 32 + q];
        ((float4*)Hs)[i] = h;
    }

    float4 acc[8];
#pragma unroll
    for (int r = 0; r < 8; ++r) acc[r] = make_float4(0.f, 0.f, 0.f, 0.f);

    for (int kc = 0; kc < 2; ++kc) {
        __syncthreads();
        for (int i = tid; i < 64 * 32; i += 256)
            ((float4*)Wsh)[i] = ((const float4*)W)[kc * 64 * 32 + i];
        __syncthreads();

#pragma unroll
        for (int kb = 0; kb < 16; ++kb) {
            const int k = kb * 4;  // k within this chunk
            float4 w0 = *(const float4*)&Wsh[(k + 0) * 128 + tc * 4];
            float4 w1 = *(const float4*)&Wsh[(k + 1) * 128 + tc * 4];
            float4 w2 = *(const float4*)&Wsh[(k + 2) * 128 + tc * 4];
            float4 w3 = *(const float4*)&Wsh[(k + 3) * 128 + tc * 4];
#pragma unroll
            for (int r = 0; r < 8; ++r) {
                float4 h = *(const float4*)&Hs[(tr * 8 + r) * 128 + kc * 64 + k];
                acc[r].x += h.x * w0.x + h.y * w1.x + h.z * w2.x + h.w * w3.x;
                acc[r].y += h.x * w0.y + h.y * w1.y + h.z * w2.y + h.w * w3.y;
                acc[r].z += h.x * w0.z + h.y * w1.z + h.z * w2.z + h.w * w3.z;
                acc[r].w += h.x * w0.w + h.y * w1.w + h.z * w2.w + h.w * w3.w;
            }
        }
    }

    const float4 bias = *(const float4*)&b[tc * 4];
#pragma unroll
    for (int r = 0; r < 8; ++r) {
        int gr = row0 + tr * 8 + r;
        if (gr < N) {
            float4 v = acc[r];
            v.x += bias.x; v.y += bias.y; v.z += bias.z; v.w += bias.w;
            v.x = v.x > 0.f ? v.x : v.x * NEG_SLOPE;
            v.y = v.y > 0.f ? v.y : v.y * NEG_SLOPE;
            v.z = v.z > 0.f ? v.z : v.z * NEG_SLOPE;
            v.w = v.w > 0.f ? v.w : v.w * NEG_SLOPE;
            *(float4*)&out[(long long)gr * 128 + tc * 4] = v;
        }
    }
}

extern "C" void kernel_launch(void* const* d_in, const int* in_sizes, int n_in,
                              void* d_out, int out_size, void* d_ws, size_t ws_size,
                              hipStream_t stream) {
    const float* feat = (const float*)d_in[0];
    const int*   edges = (const int*)d_in[1];
    const float* W1 = (const float*)d_in[2];
    const float* b1 = (const float*)d_in[3];
    const float* W2 = (const float*)d_in[4];
    const float* b2 = (const float*)d_in[5];
    float* out = (float*)d_out;

    const int N = in_sizes[0] / 128;
    const int E = in_sizes[1] / 2;
    const int* src = edges;
    const int* dst = edges + E;

    // Workspace layout (H first for 16B alignment of float4 loads):
    //   H:       N*128 floats  (51.2 MB)
    //   offsets: N+1 ints
    //   counts:  N ints   (becomes cursor after scan_write)
    //   bsum:    128 ints (scan block partials)
    //   csr:     E ints   (6.4 MB)
    float* H       = (float*)d_ws;
    int*   offsets = (int*)(H + (size_t)N * 128);
    int*   counts  = offsets + (N + 1);     // aliased as cursor
    int*   bsum    = counts + N;
    int*   csr     = bsum + 128;

    const int nb = (N + SCAN_CHUNK - 1) / SCAN_CHUNK;   // 98 for N=100k

    // ---- Build CSR (dst -> list of src), shared by both layers ----
    hipMemsetAsync(counts, 0, (size_t)N * sizeof(int), stream);
    count_kernel<<<(E + 255) / 256, 256, 0, stream>>>(dst, counts, E);
    scan_reduce<<<nb, 256, 0, stream>>>(counts, bsum, N);
    scan_top<<<1, 128, 0, stream>>>(bsum, offsets, nb, N);
    scan_write<<<nb, 256, 0, stream>>>(counts, bsum, offsets, counts, N);
    fill_kernel<<<(E + 255) / 256, 256, 0, stream>>>(src, dst, counts, csr, E);

    const int aggGrid = (N + 3) / 4;   // 4 nodes (waves) per 256-thread block
    const int gemmGrid = (N + 63) / 64;

    // ---- Layer 1 ----
    aggregate_kernel<<<aggGrid, 256, 0, stream>>>(feat, offsets, csr, H, N);
    fused_gemm<<<gemmGrid, 256, 0, stream>>>(H, W1, b1, out, N);

    // ---- Layer 2 ----
    aggregate_kernel<<<aggGrid, 256, 0, stream>>>(out, offsets, csr, H, N);
    fused_gemm<<<gemmGrid, 256, 0, stream>>>(H, W2, b2, out, N);
}

// Round 5
// 683.068 us; speedup vs baseline: 8.6254x; 1.1299x over previous
//
#include <hip/hip_runtime.h>

#define NEG_SLOPE 0.01f
#define SCAN_CHUNK 1024   // counts per block in the node-offset scan
#define BSHIFT 8          // nodes per dst-bucket = 256
#define BMAX 512          // LDS histogram capacity (supports N <= 131072)

// ---------------------------------------------------------------------------
// Bucket histogram: bcnt[b] = #edges with dst>>BSHIFT == b (LDS-aggregated)
// ---------------------------------------------------------------------------
__global__ __launch_bounds__(256) void bhist_kernel(const int* __restrict__ dst,
                                                    int* __restrict__ bcnt,
                                                    int E, int B) {
    __shared__ int h[BMAX];
    for (int i = threadIdx.x; i < B; i += 256) h[i] = 0;
    __syncthreads();
    const int stride = gridDim.x * blockDim.x;
    for (int e = blockIdx.x * blockDim.x + threadIdx.x; e < E; e += stride)
        atomicAdd(&h[dst[e] >> BSHIFT], 1);
    __syncthreads();
    for (int i = threadIdx.x; i < B; i += 256)
        if (h[i]) atomicAdd(&bcnt[i], h[i]);
}

// ---------------------------------------------------------------------------
// Exclusive scan of B (<=512) bucket counts -> bcursor
// ---------------------------------------------------------------------------
__global__ __launch_bounds__(512) void bscan_kernel(const int* __restrict__ bcnt,
                                                    int* __restrict__ bcursor, int B) {
    __shared__ int sh[512];
    const int t = threadIdx.x;
    int v = (t < B) ? bcnt[t] : 0;
    sh[t] = v;
    __syncthreads();
    for (int d = 1; d < 512; d <<= 1) {
        int u = (t >= d) ? sh[t - d] : 0;
        __syncthreads();
        sh[t] += u;
        __syncthreads();
    }
    if (t < B) bcursor[t] = sh[t] - v;
}

// ---------------------------------------------------------------------------
// Bucket scatter: pairs[pos] = (src,dst), bucket-contiguous. Two-level
// reservation: LDS histogram per block -> one global atomic per (block,bucket)
// -> LDS cursors. Writes land in ~128B runs per bucket per block.
// ---------------------------------------------------------------------------
__global__ __launch_bounds__(256) void bscatter_kernel(const int* __restrict__ src,
                                                       const int* __restrict__ dst,
                                                       int* __restrict__ bcursor,
                                                       int2* __restrict__ pairs,
                                                       int E, int B) {
    __shared__ int h[BMAX];
    __shared__ int base[BMAX];
    const int t = threadIdx.x;
    for (int i = t; i < B; i += 256) h[i] = 0;
    __syncthreads();
    const int chunk = (E + gridDim.x - 1) / gridDim.x;
    const int e0 = blockIdx.x * chunk;
    const int e1 = min(e0 + chunk, E);
    for (int e = e0 + t; e < e1; e += 256)
        atomicAdd(&h[dst[e] >> BSHIFT], 1);
    __syncthreads();
    for (int i = t; i < B; i += 256) {
        int c = h[i];
        base[i] = c ? atomicAdd(&bcursor[i], c) : 0;
    }
    __syncthreads();
    for (int i = t; i < B; i += 256) h[i] = base[i];
    __syncthreads();
    for (int e = e0 + t; e < e1; e += 256) {
        int d = dst[e];
        int pos = atomicAdd(&h[d >> BSHIFT], 1);
        pairs[pos] = make_int2(src[e], d);
    }
}

// ---------------------------------------------------------------------------
// counts[dst] += 1 over bucket-sorted pairs (atomics hit a ~1KB moving window)
// ---------------------------------------------------------------------------
__global__ __launch_bounds__(256) void count2_kernel(const int2* __restrict__ pairs,
                                                     int* __restrict__ counts, int E) {
    int e = blockIdx.x * blockDim.x + threadIdx.x;
    if (e < E) atomicAdd(&counts[pairs[e].y], 1);
}

// ---------------------------------------------------------------------------
// Node-offset scan (3 phases, unchanged from round 3)
// ---------------------------------------------------------------------------
__global__ __launch_bounds__(256) void scan_reduce(const int* __restrict__ counts,
                                                   int* __restrict__ bsum, int N) {
    __shared__ int red[256];
    const int t = threadIdx.x;
    const int base = blockIdx.x * SCAN_CHUNK + t * 4;
    int s = 0;
#pragma unroll
    for (int k = 0; k < 4; ++k) {
        int i = base + k;
        if (i < N) s += counts[i];
    }
    red[t] = s;
    __syncthreads();
    for (int d = 128; d > 0; d >>= 1) {
        if (t < d) red[t] += red[t + d];
        __syncthreads();
    }
    if (t == 0) bsum[blockIdx.x] = red[0];
}

__global__ __launch_bounds__(128) void scan_top(int* __restrict__ bsum,
                                                int* __restrict__ offsets,
                                                int nb, int N) {
    __shared__ int sh[128];
    const int t = threadIdx.x;
    int v = (t < nb) ? bsum[t] : 0;
    sh[t] = v;
    __syncthreads();
    for (int d = 1; d < 128; d <<= 1) {
        int u = (t >= d) ? sh[t - d] : 0;
        __syncthreads();
        sh[t] += u;
        __syncthreads();
    }
    if (t < nb) bsum[t] = sh[t] - v;
    if (t == 127) offsets[N] = sh[127];
}

__global__ __launch_bounds__(256) void scan_write(const int* __restrict__ counts,
                                                  const int* __restrict__ bsum,
                                                  int* __restrict__ offsets,
                                                  int* __restrict__ cursor, int N) {
    __shared__ int sh[256];
    const int t = threadIdx.x;
    const int base = blockIdx.x * SCAN_CHUNK + t * 4;
    int c[4];
    int s = 0;
#pragma unroll
    for (int k = 0; k < 4; ++k) {
        int i = base + k;
        c[k] = (i < N) ? counts[i] : 0;
        s += c[k];
    }
    sh[t] = s;
    __syncthreads();
    for (int d = 1; d < 256; d <<= 1) {
        int u = (t >= d) ? sh[t - d] : 0;
        __syncthreads();
        sh[t] += u;
        __syncthreads();
    }
    int run = bsum[blockIdx.x] + sh[t] - s;
#pragma unroll
    for (int k = 0; k < 4; ++k) {
        int i = base + k;
        if (i < N) {
            offsets[i] = run;
            cursor[i] = run;
            run += c[k];
        }
    }
}

// ---------------------------------------------------------------------------
// Final fill from bucket-sorted pairs: csr writes stay in a ~16KB window per
// bucket -> L2 lines fill fully before eviction.
// ---------------------------------------------------------------------------
__global__ __launch_bounds__(256) void fillB_kernel(const int2* __restrict__ pairs,
                                                    int* __restrict__ cursor,
                                                    int* __restrict__ csr, int E) {
    int e = blockIdx.x * blockDim.x + threadIdx.x;
    if (e < E) {
        int2 p = pairs[e];
        int pos = atomicAdd(&cursor[p.y], 1);
        csr[pos] = p.x;
    }
}

// ---------------------------------------------------------------------------
// H[n][:] = (x[n][:] + sum_neighbors x[s][:]) / (deg+1)
// One wave per node, float2 per lane, 4-way unrolled for MLP.
// ---------------------------------------------------------------------------
__global__ __launch_bounds__(256) void aggregate_kernel(const float* __restrict__ x,
                                                        const int* __restrict__ offsets,
                                                        const int* __restrict__ csr,
                                                        float* __restrict__ H, int N) {
    const int node = (blockIdx.x * blockDim.x + threadIdx.x) >> 6;
    const int lane = threadIdx.x & 63;
    if (node >= N) return;
    const int start = offsets[node];
    const int end   = offsets[node + 1];
    const float2* x2 = (const float2*)x;

    float2 a0 = x2[(long long)node * 64 + lane];  // self feature
    float2 a1 = make_float2(0.f, 0.f);
    float2 a2 = make_float2(0.f, 0.f);
    float2 a3 = make_float2(0.f, 0.f);
    int j = start;
    for (; j + 4 <= end; j += 4) {
        int s0 = csr[j];
        int s1 = csr[j + 1];
        int s2 = csr[j + 2];
        int s3 = csr[j + 3];
        float2 v0 = x2[(long long)s0 * 64 + lane];
        float2 v1 = x2[(long long)s1 * 64 + lane];
        float2 v2 = x2[(long long)s2 * 64 + lane];
        float2 v3 = x2[(long long)s3 * 64 + lane];
        a0.x += v0.x; a0.y += v0.y;
        a1.x += v1.x; a1.y += v1.y;
        a2.x += v2.x; a2.y += v2.y;
        a3.x += v3.x; a3.y += v3.y;
    }
    for (; j < end; ++j) {
        int s0 = csr[j];
        float2 v0 = x2[(long long)s0 * 64 + lane];
        a0.x += v0.x; a0.y += v0.y;
    }
    const float inv = 1.0f / (float)(end - start + 1);
    float2 r;
    r.x = ((a0.x + a1.x) + (a2.x + a3.x)) * inv;
    r.y = ((a0.y + a1.y) + (a2.y + a3.y)) * inv;
    ((float2*)H)[(long long)node * 64 + lane] = r;
}

// ---------------------------------------------------------------------------
// out[r][c] = leaky( sum_k H[r][k] * W[k][c] + b[c] )   (round-4 version)
// ---------------------------------------------------------------------------
__global__ __launch_bounds__(256) void fused_gemm(const float* __restrict__ H,
                                                  const float* __restrict__ W,
                                                  const float* __restrict__ b,
                                                  float* __restrict__ out, int N) {
    __shared__ float Hs[64 * 128];
    __shared__ float Wsh[64 * 128];
    const int tid = threadIdx.x;
    const int row0 = blockIdx.x * 64;
    const int tr = tid >> 5;
    const int tc = tid & 31;

    for (int i = tid; i < 64 * 32; i += 256) {
        int r = i >> 5, q = i & 31;
        int gr = row0 + r;
        float4 h = make_float4(0.f, 0.f, 0.f, 0.f);
        if (gr < N) h = ((const float4*)H)[(long long)gr * 32 + q];
        ((float4*)Hs)[i] = h;
    }

    float4 acc[8];
#pragma unroll
    for (int r = 0; r < 8; ++r) acc[r] = make_float4(0.f, 0.f, 0.f, 0.f);

    for (int kc = 0; kc < 2; ++kc) {
        __syncthreads();
        for (int i = tid; i < 64 * 32; i += 256)
            ((float4*)Wsh)[i] = ((const float4*)W)[kc * 64 * 32 + i];
        __syncthreads();

#pragma unroll
        for (int kb = 0; kb < 16; ++kb) {
            const int k = kb * 4;
            float4 w0 = *(const float4*)&Wsh[(k + 0) * 128 + tc * 4];
            float4 w1 = *(const float4*)&Wsh[(k + 1) * 128 + tc * 4];
            float4 w2 = *(const float4*)&Wsh[(k + 2) * 128 + tc * 4];
            float4 w3 = *(const float4*)&Wsh[(k + 3) * 128 + tc * 4];
#pragma unroll
            for (int r = 0; r < 8; ++r) {
                float4 h = *(const float4*)&Hs[(tr * 8 + r) * 128 + kc * 64 + k];
                acc[r].x += h.x * w0.x + h.y * w1.x + h.z * w2.x + h.w * w3.x;
                acc[r].y += h.x * w0.y + h.y * w1.y + h.z * w2.y + h.w * w3.y;
                acc[r].z += h.x * w0.z + h.y * w1.z + h.z * w2.z + h.w * w3.z;
                acc[r].w += h.x * w0.w + h.y * w1.w + h.z * w2.w + h.w * w3.w;
            }
        }
    }

    const float4 bias = *(const float4*)&b[tc * 4];
#pragma unroll
    for (int r = 0; r < 8; ++r) {
        int gr = row0 + tr * 8 + r;
        if (gr < N) {
            float4 v = acc[r];
            v.x += bias.x; v.y += bias.y; v.z += bias.z; v.w += bias.w;
            v.x = v.x > 0.f ? v.x : v.x * NEG_SLOPE;
            v.y = v.y > 0.f ? v.y : v.y * NEG_SLOPE;
            v.z = v.z > 0.f ? v.z : v.z * NEG_SLOPE;
            v.w = v.w > 0.f ? v.w : v.w * NEG_SLOPE;
            *(float4*)&out[(long long)gr * 128 + tc * 4] = v;
        }
    }
}

extern "C" void kernel_launch(void* const* d_in, const int* in_sizes, int n_in,
                              void* d_out, int out_size, void* d_ws, size_t ws_size,
                              hipStream_t stream) {
    const float* feat = (const float*)d_in[0];
    const int*   edges = (const int*)d_in[1];
    const float* W1 = (const float*)d_in[2];
    const float* b1 = (const float*)d_in[3];
    const float* W2 = (const float*)d_in[4];
    const float* b2 = (const float*)d_in[5];
    float* out = (float*)d_out;

    const int N = in_sizes[0] / 128;
    const int E = in_sizes[1] / 2;
    const int* src = edges;
    const int* dst = edges + E;
    const int B = (N + (1 << BSHIFT) - 1) >> BSHIFT;   // 391 for N=100k (<=BMAX)

    // Workspace layout:
    //   H:       N*128 floats (51.2 MB)  -- pairs (E int2, 12.8 MB) aliased here
    //   offsets: N+1 ints
    //   counts:  N ints   (becomes cursor after scan_write)
    //   bcnt:    B ints   (contiguous with counts for one memset)
    //   bcursor: B ints
    //   bsum:    128 ints
    //   csr:     E ints (6.4 MB)
    float* H       = (float*)d_ws;
    int2*  pairs   = (int2*)d_ws;           // dead before aggregate runs
    int*   offsets = (int*)(H + (size_t)N * 128);
    int*   counts  = offsets + (N + 1);
    int*   bcnt    = counts + N;
    int*   bcursor = bcnt + B;
    int*   bsum    = bcursor + B;
    int*   csr     = bsum + 128;

    const int nb = (N + SCAN_CHUNK - 1) / SCAN_CHUNK;

    // ---- Build CSR (dst -> list of src) via bucket radix ----
    hipMemsetAsync(counts, 0, (size_t)(N + B) * sizeof(int), stream);  // counts+bcnt
    bhist_kernel<<<256, 256, 0, stream>>>(dst, bcnt, E, B);
    bscan_kernel<<<1, 512, 0, stream>>>(bcnt, bcursor, B);
    bscatter_kernel<<<256, 256, 0, stream>>>(src, dst, bcursor, pairs, E, B);
    count2_kernel<<<(E + 255) / 256, 256, 0, stream>>>(pairs, counts, E);
    scan_reduce<<<nb, 256, 0, stream>>>(counts, bsum, N);
    scan_top<<<1, 128, 0, stream>>>(bsum, offsets, nb, N);
    scan_write<<<nb, 256, 0, stream>>>(counts, bsum, offsets, counts, N);
    fillB_kernel<<<(E + 255) / 256, 256, 0, stream>>>(pairs, counts, csr, E);

    const int aggGrid = (N + 3) / 4;
    const int gemmGrid = (N + 63) / 64;

    // ---- Layer 1 ----
    aggregate_kernel<<<aggGrid, 256, 0, stream>>>(feat, offsets, csr, H, N);
    fused_gemm<<<gemmGrid, 256, 0, stream>>>(H, W1, b1, out, N);

    // ---- Layer 2 ----
    aggregate_kernel<<<aggGrid, 256, 0, stream>>>(out, offsets, csr, H, N);
    fused_gemm<<<gemmGrid, 256, 0, stream>>>(H, W2, b2, out, N);
}

// Round 6
// 436.002 us; speedup vs baseline: 13.5131x; 1.5667x over previous
//
#include <hip/hip_runtime.h>

#define NEG_SLOPE 0.01f
#define SCAN_CHUNK 1024   // counts per block in the node-offset scan
#define BSHIFT 8          // nodes per dst-bucket = 256
#define BMAX 512          // LDS histogram capacity (supports N <= 131072)

typedef __attribute__((ext_vector_type(8))) short bf16x8;
typedef __attribute__((ext_vector_type(4))) float f32x4;

// fp32 -> bf16 (RNE, normals only — fine for this data)
static __device__ inline unsigned short f2b(float f) {
    unsigned u = __builtin_bit_cast(unsigned, f);
    return (unsigned short)((u + 0x7FFF + ((u >> 16) & 1)) >> 16);
}
static __device__ inline float b2f_lo(unsigned u) {
    return __builtin_bit_cast(float, u << 16);
}
static __device__ inline float b2f_hi(unsigned u) {
    return __builtin_bit_cast(float, u & 0xFFFF0000u);
}

// ---------------------------------------------------------------------------
// feat fp32 -> bf16 (N*128 elements, multiple of 4)
// ---------------------------------------------------------------------------
__global__ __launch_bounds__(256) void cvt_feat(const float* __restrict__ x,
                                                unsigned short* __restrict__ xb,
                                                long long n) {
    long long i = ((long long)blockIdx.x * 256 + threadIdx.x) * 4;
    if (i < n) {
        float4 v = *(const float4*)(x + i);
        ushort4 o;
        o.x = f2b(v.x); o.y = f2b(v.y); o.z = f2b(v.z); o.w = f2b(v.w);
        *(ushort4*)(xb + i) = o;
    }
}

// ---------------------------------------------------------------------------
// W[k][n] fp32 -> Wt[n][k] bf16, both layers (128x128 each; tiny one-time cost)
// ---------------------------------------------------------------------------
__global__ __launch_bounds__(256) void cvt_w(const float* __restrict__ W1,
                                             const float* __restrict__ W2,
                                             unsigned short* __restrict__ Wt1,
                                             unsigned short* __restrict__ Wt2) {
    int i = blockIdx.x * 256 + threadIdx.x;   // 0..16383
    int n = i & 127, k = i >> 7;
    Wt1[n * 128 + k] = f2b(W1[k * 128 + n]);
    Wt2[n * 128 + k] = f2b(W2[k * 128 + n]);
}

// ---------------------------------------------------------------------------
// Bucket histogram: bcnt[b] = #edges with dst>>BSHIFT == b (LDS-aggregated)
// ---------------------------------------------------------------------------
__global__ __launch_bounds__(256) void bhist_kernel(const int* __restrict__ dst,
                                                    int* __restrict__ bcnt,
                                                    int E, int B) {
    __shared__ int h[BMAX];
    for (int i = threadIdx.x; i < B; i += 256) h[i] = 0;
    __syncthreads();
    const int stride = gridDim.x * blockDim.x;
    for (int e = blockIdx.x * blockDim.x + threadIdx.x; e < E; e += stride)
        atomicAdd(&h[dst[e] >> BSHIFT], 1);
    __syncthreads();
    for (int i = threadIdx.x; i < B; i += 256)
        if (h[i]) atomicAdd(&bcnt[i], h[i]);
}

__global__ __launch_bounds__(512) void bscan_kernel(const int* __restrict__ bcnt,
                                                    int* __restrict__ bcursor, int B) {
    __shared__ int sh[512];
    const int t = threadIdx.x;
    int v = (t < B) ? bcnt[t] : 0;
    sh[t] = v;
    __syncthreads();
    for (int d = 1; d < 512; d <<= 1) {
        int u = (t >= d) ? sh[t - d] : 0;
        __syncthreads();
        sh[t] += u;
        __syncthreads();
    }
    if (t < B) bcursor[t] = sh[t] - v;
}

__global__ __launch_bounds__(256) void bscatter_kernel(const int* __restrict__ src,
                                                       const int* __restrict__ dst,
                                                       int* __restrict__ bcursor,
                                                       int2* __restrict__ pairs,
                                                       int E, int B) {
    __shared__ int h[BMAX];
    __shared__ int base[BMAX];
    const int t = threadIdx.x;
    for (int i = t; i < B; i += 256) h[i] = 0;
    __syncthreads();
    const int chunk = (E + gridDim.x - 1) / gridDim.x;
    const int e0 = blockIdx.x * chunk;
    const int e1 = min(e0 + chunk, E);
    for (int e = e0 + t; e < e1; e += 256)
        atomicAdd(&h[dst[e] >> BSHIFT], 1);
    __syncthreads();
    for (int i = t; i < B; i += 256) {
        int c = h[i];
        base[i] = c ? atomicAdd(&bcursor[i], c) : 0;
    }
    __syncthreads();
    for (int i = t; i < B; i += 256) h[i] = base[i];
    __syncthreads();
    for (int e = e0 + t; e < e1; e += 256) {
        int d = dst[e];
        int pos = atomicAdd(&h[d >> BSHIFT], 1);
        pairs[pos] = make_int2(src[e], d);
    }
}

__global__ __launch_bounds__(256) void count2_kernel(const int2* __restrict__ pairs,
                                                     int* __restrict__ counts, int E) {
    int e = blockIdx.x * blockDim.x + threadIdx.x;
    if (e < E) atomicAdd(&counts[pairs[e].y], 1);
}

// ---------------------------------------------------------------------------
// Node-offset scan (3 phases)
// ---------------------------------------------------------------------------
__global__ __launch_bounds__(256) void scan_reduce(const int* __restrict__ counts,
                                                   int* __restrict__ bsum, int N) {
    __shared__ int red[256];
    const int t = threadIdx.x;
    const int base = blockIdx.x * SCAN_CHUNK + t * 4;
    int s = 0;
#pragma unroll
    for (int k = 0; k < 4; ++k) {
        int i = base + k;
        if (i < N) s += counts[i];
    }
    red[t] = s;
    __syncthreads();
    for (int d = 128; d > 0; d >>= 1) {
        if (t < d) red[t] += red[t + d];
        __syncthreads();
    }
    if (t == 0) bsum[blockIdx.x] = red[0];
}

__global__ __launch_bounds__(128) void scan_top(int* __restrict__ bsum,
                                                int* __restrict__ offsets,
                                                int nb, int N) {
    __shared__ int sh[128];
    const int t = threadIdx.x;
    int v = (t < nb) ? bsum[t] : 0;
    sh[t] = v;
    __syncthreads();
    for (int d = 1; d < 128; d <<= 1) {
        int u = (t >= d) ? sh[t - d] : 0;
        __syncthreads();
        sh[t] += u;
        __syncthreads();
    }
    if (t < nb) bsum[t] = sh[t] - v;
    if (t == 127) offsets[N] = sh[127];
}

__global__ __launch_bounds__(256) void scan_write(const int* __restrict__ counts,
                                                  const int* __restrict__ bsum,
                                                  int* __restrict__ offsets,
                                                  int* __restrict__ cursor, int N) {
    __shared__ int sh[256];
    const int t = threadIdx.x;
    const int base = blockIdx.x * SCAN_CHUNK + t * 4;
    int c[4];
    int s = 0;
#pragma unroll
    for (int k = 0; k < 4; ++k) {
        int i = base + k;
        c[k] = (i < N) ? counts[i] : 0;
        s += c[k];
    }
    sh[t] = s;
    __syncthreads();
    for (int d = 1; d < 256; d <<= 1) {
        int u = (t >= d) ? sh[t - d] : 0;
        __syncthreads();
        sh[t] += u;
        __syncthreads();
    }
    int run = bsum[blockIdx.x] + sh[t] - s;
#pragma unroll
    for (int k = 0; k < 4; ++k) {
        int i = base + k;
        if (i < N) {
            offsets[i] = run;
            cursor[i] = run;
            run += c[k];
        }
    }
}

__global__ __launch_bounds__(256) void fillB_kernel(const int2* __restrict__ pairs,
                                                    int* __restrict__ cursor,
                                                    int* __restrict__ csr, int E) {
    int e = blockIdx.x * blockDim.x + threadIdx.x;
    if (e < E) {
        int2 p = pairs[e];
        int pos = atomicAdd(&cursor[p.y], 1);
        csr[pos] = p.x;
    }
}

// ---------------------------------------------------------------------------
// Hb[n][:] = bf16( (xb[n][:] + sum_neighbors xb[s][:]) / (deg+1) )
// One wave per node; lane handles 2 cols packed in one uint; fp32 accum.
// ---------------------------------------------------------------------------
__global__ __launch_bounds__(256) void aggregate_kernel(const unsigned short* __restrict__ xb,
                                                        const int* __restrict__ offsets,
                                                        const int* __restrict__ csr,
                                                        unsigned short* __restrict__ Hb,
                                                        int N) {
    const int node = (blockIdx.x * blockDim.x + threadIdx.x) >> 6;
    const int lane = threadIdx.x & 63;
    if (node >= N) return;
    const int start = offsets[node];
    const int end   = offsets[node + 1];
    const unsigned* x1 = (const unsigned*)xb;   // 2 bf16 per uint

    unsigned us = x1[(long long)node * 64 + lane];
    float a0 = b2f_lo(us), c0 = b2f_hi(us);
    float a1 = 0.f, c1 = 0.f, a2 = 0.f, c2 = 0.f, a3 = 0.f, c3 = 0.f;
    int j = start;
    for (; j + 4 <= end; j += 4) {
        int s0 = csr[j], s1 = csr[j + 1], s2 = csr[j + 2], s3 = csr[j + 3];
        unsigned u0 = x1[(long long)s0 * 64 + lane];
        unsigned u1 = x1[(long long)s1 * 64 + lane];
        unsigned u2 = x1[(long long)s2 * 64 + lane];
        unsigned u3 = x1[(long long)s3 * 64 + lane];
        a0 += b2f_lo(u0); c0 += b2f_hi(u0);
        a1 += b2f_lo(u1); c1 += b2f_hi(u1);
        a2 += b2f_lo(u2); c2 += b2f_hi(u2);
        a3 += b2f_lo(u3); c3 += b2f_hi(u3);
    }
    for (; j < end; ++j) {
        unsigned u0 = x1[(long long)csr[j] * 64 + lane];
        a0 += b2f_lo(u0); c0 += b2f_hi(u0);
    }
    const float inv = 1.0f / (float)(end - start + 1);
    float rx = ((a0 + a1) + (a2 + a3)) * inv;
    float ry = ((c0 + c1) + (c2 + c3)) * inv;
    unsigned o = (unsigned)f2b(rx) | ((unsigned)f2b(ry) << 16);
    ((unsigned*)Hb)[(long long)node * 64 + lane] = o;
}

// ---------------------------------------------------------------------------
// MFMA GEMM: out[r][c] = leaky( sum_k H[r][k] * W[k][c] + b[c] )
// 128 rows x 128 cols per block, 256 threads = 4 waves; wave w covers rows
// w*32..w*32+31 as 2 row-tiles x 8 col-tiles of 16x16x32 bf16 MFMA.
// LDS: Ha[128 rows][16 chunks], Wa[128 n][16 chunks], chunk=16B, XOR-swizzled
// (phys chunk = c ^ (row&15)) -> all b128 reads/writes are 2-way = conflict-free.
// A-frag: A[m=lane&15][k=quad*8+j]; B-frag: B[k=quad*8+j][n=lane&15] via Wt[n][k];
// C/D: col=lane&15, row=quad*4+reg (HW-verified layouts).
// ---------------------------------------------------------------------------
template <bool OUT_BF16>
__global__ __launch_bounds__(256) void gemm_mfma(const unsigned short* __restrict__ Hb,
                                                 const unsigned short* __restrict__ Wt,
                                                 const float* __restrict__ b,
                                                 void* __restrict__ outv, int N) {
    __shared__ unsigned short Ha[128 * 128];  // 32 KB
    __shared__ unsigned short Wa[128 * 128];  // 32 KB
    const int tid = threadIdx.x;
    const int row0 = blockIdx.x * 128;

    // Stage Ha (2048 16B chunks) — global reads coalesced, LDS writes swizzled
#pragma unroll
    for (int it = 0; it < 8; ++it) {
        int idx = it * 256 + tid;
        int r = idx >> 4, c = idx & 15;
        int gr = row0 + r;
        uint4 v = make_uint4(0, 0, 0, 0);
        if (gr < N) v = *(const uint4*)(Hb + (long long)gr * 128 + c * 8);
        *(uint4*)(Ha + r * 128 + ((c ^ (r & 15)) << 3)) = v;
    }
    // Stage Wa (Wt is [n][k] bf16, 2048 chunks)
#pragma unroll
    for (int it = 0; it < 8; ++it) {
        int idx = it * 256 + tid;
        int r = idx >> 4, c = idx & 15;
        uint4 v = *(const uint4*)(Wt + r * 128 + c * 8);
        *(uint4*)(Wa + r * 128 + ((c ^ (r & 15)) << 3)) = v;
    }
    __syncthreads();

    const int w = tid >> 6;
    const int lane = tid & 63;
    const int m = lane & 15;   // A row-in-tile / B col-in-tile / C col
    const int q = lane >> 4;   // quad

    f32x4 acc[2][8];
#pragma unroll
    for (int rt = 0; rt < 2; ++rt)
#pragma unroll
        for (int ct = 0; ct < 8; ++ct) acc[rt][ct] = (f32x4){0.f, 0.f, 0.f, 0.f};

#pragma unroll
    for (int kk = 0; kk < 4; ++kk) {
        const int chunk = kk * 4 + q;  // this lane's 16B chunk (8 bf16 of k)
        bf16x8 af[2];
#pragma unroll
        for (int rt = 0; rt < 2; ++rt) {
            int r = w * 32 + rt * 16 + m;
            af[rt] = *(const bf16x8*)(Ha + r * 128 + ((chunk ^ (r & 15)) << 3));
        }
#pragma unroll
        for (int ct = 0; ct < 8; ++ct) {
            int n = ct * 16 + m;
            bf16x8 bfr = *(const bf16x8*)(Wa + n * 128 + ((chunk ^ (n & 15)) << 3));
            acc[0][ct] = __builtin_amdgcn_mfma_f32_16x16x32_bf16(af[0], bfr, acc[0][ct], 0, 0, 0);
            acc[1][ct] = __builtin_amdgcn_mfma_f32_16x16x32_bf16(af[1], bfr, acc[1][ct], 0, 0, 0);
        }
    }

    // Epilogue: bias + leaky-relu, store (fp32 or bf16)
#pragma unroll
    for (int ct = 0; ct < 8; ++ct) {
        const float bias = b[ct * 16 + m];
        const int gcol = ct * 16 + m;
#pragma unroll
        for (int rt = 0; rt < 2; ++rt) {
#pragma unroll
            for (int reg = 0; reg < 4; ++reg) {
                int grow = row0 + w * 32 + rt * 16 + q * 4 + reg;
                if (grow < N) {
                    float v = acc[rt][ct][reg] + bias;
                    v = v > 0.f ? v : v * NEG_SLOPE;
                    if (OUT_BF16)
                        ((unsigned short*)outv)[(long long)grow * 128 + gcol] = f2b(v);
                    else
                        ((float*)outv)[(long long)grow * 128 + gcol] = v;
                }
            }
        }
    }
}

extern "C" void kernel_launch(void* const* d_in, const int* in_sizes, int n_in,
                              void* d_out, int out_size, void* d_ws, size_t ws_size,
                              hipStream_t stream) {
    const float* feat = (const float*)d_in[0];
    const int*   edges = (const int*)d_in[1];
    const float* W1 = (const float*)d_in[2];
    const float* b1 = (const float*)d_in[3];
    const float* W2 = (const float*)d_in[4];
    const float* b2 = (const float*)d_in[5];
    float* out = (float*)d_out;

    const int N = in_sizes[0] / 128;
    const int E = in_sizes[1] / 2;
    const int* src = edges;
    const int* dst = edges + E;
    const int B = (N + (1 << BSHIFT) - 1) >> BSHIFT;

    // Workspace layout (all 16B-aligned):
    //   featb:  N*128 bf16 (25.6 MB) — feat bf16; REUSED as h1b after aggregate-1
    //   Hb:     N*128 bf16 (25.6 MB) — aggregated features; pairs (E int2) aliased
    //   Wt1,Wt2: 128*128 bf16 each
    //   offsets/counts/bcnt/bcursor/bsum/csr: ints
    unsigned short* featb = (unsigned short*)d_ws;
    unsigned short* Hb    = featb + (size_t)N * 128;
    int2*           pairs = (int2*)Hb;              // dead before aggregate-1
    unsigned short* Wt1   = Hb + (size_t)N * 128;
    unsigned short* Wt2   = Wt1 + 128 * 128;
    int* offsets = (int*)(Wt2 + 128 * 128);
    int* counts  = offsets + (N + 1);
    int* bcnt    = counts + N;
    int* bcursor = bcnt + B;
    int* bsum    = bcursor + B;
    int* csr     = bsum + 128;

    const int nb = (N + SCAN_CHUNK - 1) / SCAN_CHUNK;

    // ---- dtype conversions (independent of CSR build) ----
    long long nfeat = (long long)N * 128;
    cvt_feat<<<(int)((nfeat / 4 + 255) / 256), 256, 0, stream>>>(feat, featb, nfeat);
    cvt_w<<<64, 256, 0, stream>>>(W1, W2, Wt1, Wt2);

    // ---- Build CSR (dst -> list of src) via bucket radix ----
    hipMemsetAsync(counts, 0, (size_t)(N + B) * sizeof(int), stream);
    bhist_kernel<<<256, 256, 0, stream>>>(dst, bcnt, E, B);
    bscan_kernel<<<1, 512, 0, stream>>>(bcnt, bcursor, B);
    bscatter_kernel<<<256, 256, 0, stream>>>(src, dst, bcursor, pairs, E, B);
    count2_kernel<<<(E + 255) / 256, 256, 0, stream>>>(pairs, counts, E);
    scan_reduce<<<nb, 256, 0, stream>>>(counts, bsum, N);
    scan_top<<<1, 128, 0, stream>>>(bsum, offsets, nb, N);
    scan_write<<<nb, 256, 0, stream>>>(counts, bsum, offsets, counts, N);
    fillB_kernel<<<(E + 255) / 256, 256, 0, stream>>>(pairs, counts, csr, E);

    const int aggGrid = (N + 3) / 4;
    const int gemmGrid = (N + 127) / 128;

    // ---- Layer 1: aggregate bf16 -> Hb; GEMM writes h1 bf16 into featb ----
    aggregate_kernel<<<aggGrid, 256, 0, stream>>>(featb, offsets, csr, Hb, N);
    gemm_mfma<true><<<gemmGrid, 256, 0, stream>>>(Hb, Wt1, b1, (void*)featb, N);

    // ---- Layer 2: aggregate h1b -> Hb; GEMM writes fp32 to d_out ----
    aggregate_kernel<<<aggGrid, 256, 0, stream>>>(featb, offsets, csr, Hb, N);
    gemm_mfma<false><<<gemmGrid, 256, 0, stream>>>(Hb, Wt2, b2, (void*)out, N);
}